// Round 1
// 1291.276 us; speedup vs baseline: 1.5129x; 1.5129x over previous
//
#include <hip/hip_runtime.h>
#include <stdint.h>

// ---------------------------------------------------------------------------
// NonLinearCoSeqAttn: B=16, LX=LY=2048, D=H=1024
// R1: all big GEMMs moved to a 256x256 8-wave, 4-phase/K-tile (8-phase/iter)
// schedule (T2 swizzle + T3/T4 counted vmcnt + T5 setprio + T1 XCD swizzle).
//   - LDS 128 KiB: A/B double-buffered, K-half (32-col) staging granularity.
//   - stage = global_load_lds w16, linear dest; swizzle applied by
//     pre-swizzling the GLOBAL source column (m173/m201 pattern):
//     lds(row, cb) holds global col cb ^ ((row&3)<<4)  [bytes, 64B rows]
//   - steady-state s_waitcnt vmcnt(4) at 2-phase boundaries; vmcnt(0) only
//     in the last K-tile. Raw s_barrier (no compiler drain).
//   - projections: fast path pre-converts x,y,W to f16 (ws permitting) and
//     uses the same 256^2 kernel; else falls back to the old INRAW 128^2.
// Pipeline: detect; init; transpose(+f16 copy); [cvt W]; proj; per chunk:
//   s=mask(px@py^T)+max-atomics; transform->Pr/Pct+lsums; y_h; x_h.
// ---------------------------------------------------------------------------

typedef short    short8  __attribute__((ext_vector_type(8)));
typedef _Float16 half8   __attribute__((ext_vector_type(8)));
typedef _Float16 half4   __attribute__((ext_vector_type(4)));
typedef float    floatx4 __attribute__((ext_vector_type(4)));

static __device__ __forceinline__ float b2f(unsigned short s) {
    union { unsigned int u; float f; } v; v.u = ((unsigned int)s) << 16; return v.f;
}
static __device__ __forceinline__ _Float16 f2h(float f) { return (_Float16)f; }
static __device__ __forceinline__ unsigned fenc(float f) {
    unsigned u = __float_as_uint(f);
    return (u & 0x80000000u) ? ~u : (u | 0x80000000u);
}
static __device__ __forceinline__ float fdec(unsigned u) {
    return __uint_as_float((u & 0x80000000u) ? (u ^ 0x80000000u) : ~u);
}
#define ENC_NEGINF 0x007FFFFFu

static __device__ __forceinline__ void gl_lds16(const _Float16* g, _Float16* l) {
    __builtin_amdgcn_global_load_lds(
        (const __attribute__((address_space(1))) void*)g,
        (__attribute__((address_space(3))) void*)l, 16, 0, 0);
}

// flags[0]: 1 => masks u8, 0 => int32.  flags[1]: 1 => inputs f32, 0 => bf16.
__global__ void detect_kernel(const unsigned int* __restrict__ xm,
                              const unsigned int* __restrict__ xv,
                              int* __restrict__ flags)
{
    __shared__ int anyBig, cnt;
    if (threadIdx.x == 0) { anyBig = 0; cnt = 0; }
    __syncthreads();
    int big = 0;
    for (int i = threadIdx.x; i < 2048; i += 256)
        if (xm[i] > 1u) big = 1;
    if (big) atomicOr(&anyBig, 1);
    int c = 0;
    for (int i = threadIdx.x; i < 4096; i += 256) {
        const unsigned lo = xv[i] & 0xFFFFu;
        const unsigned e  = (lo >> 7) & 0xFFu;
        if ((lo & 0x7FFFu) == 0u || (e >= 96u && e <= 143u)) c++;
    }
    atomicAdd(&cnt, c);
    __syncthreads();
    if (threadIdx.x == 0) { flags[0] = anyBig; flags[1] = (cnt < 3600) ? 1 : 0; }
}

__global__ void init_kernel(unsigned* __restrict__ mr, float* __restrict__ lr,
                            unsigned* __restrict__ mc, float* __restrict__ lc, int n)
{
    const int i = blockIdx.x * 256 + threadIdx.x;
    if (i < n) { mr[i] = ENC_NEGINF; mc[i] = ENC_NEGINF; lr[i] = 0.f; lc[i] = 0.f; }
}

// [B][L][D] (bf16|f32) -> [B][D][L] f16 (out); optionally also straight
// f16 copy [B][L][D] (outH) for the fast projection path.
__global__ __launch_bounds__(256)
void transpose_in_kernel(const void* __restrict__ in, _Float16* __restrict__ out,
                         _Float16* __restrict__ outH, const int* __restrict__ flags)
{
    const int b = blockIdx.z, lt = blockIdx.y, dt = blockIdx.x;
    const int inf32 = flags[1];
    __shared__ _Float16 T[64 * 67];
    const int t  = threadIdx.x;
    const int r0 = t >> 3;         // 0..31
    const int c0 = (t & 7) * 8;    // 0..56
    const unsigned short* in16 = (const unsigned short*)in + (long long)b * 2048 * 1024;
    const float*          inf  = (const float*)in + (long long)b * 2048 * 1024;
    #pragma unroll
    for (int it = 0; it < 2; it++) {
        const int ll = r0 + it * 32;
        const long long src = (long long)(lt * 64 + ll) * 1024 + dt * 64 + c0;
        _Float16 v[8];
        if (inf32) {
            const float* p = inf + src;
            #pragma unroll
            for (int k = 0; k < 8; k++) v[k] = f2h(p[k]);
        } else {
            short8 r = *(const short8*)(in16 + src);
            #pragma unroll
            for (int k = 0; k < 8; k++) v[k] = f2h(b2f((unsigned short)r[k]));
        }
        if (outH) {
            half8 o;
            #pragma unroll
            for (int k = 0; k < 8; k++) o[k] = v[k];
            *(half8*)&outH[(long long)b * 2048 * 1024 + src] = o;
        }
        #pragma unroll
        for (int k = 0; k < 8; k++) T[(c0 + k) * 67 + ll] = v[k];
    }
    __syncthreads();
    #pragma unroll
    for (int it = 0; it < 2; it++) {
        const int dl = r0 + it * 32;
        half8 o;
        #pragma unroll
        for (int k = 0; k < 8; k++) o[k] = T[dl * 67 + c0 + k];
        *(half8*)&out[(long long)b * 1024 * 2048 +
                      (long long)(dt * 64 + dl) * 2048 + lt * 64 + c0] = o;
    }
}

// (bf16|f32) -> f16, n elems (multiple of 2048)
__global__ __launch_bounds__(256)
void cvt16_kernel(const void* __restrict__ in, _Float16* __restrict__ out,
                  const int* __restrict__ flags, long long n)
{
    const long long i = (((long long)blockIdx.x * 256) + threadIdx.x) << 3;
    if (i >= n) return;
    half8 o;
    if (flags[1]) {
        const float* pf = (const float*)in + i;
        #pragma unroll
        for (int k = 0; k < 8; k++) o[k] = f2h(pf[k]);
    } else {
        short8 rr = *(const short8*)((const unsigned short*)in + i);
        #pragma unroll
        for (int k = 0; k < 8; k++) o[k] = f2h(b2f((unsigned short)rr[k]));
    }
    *(half8*)&out[i] = o;
}

// Per 64x64 s-tile: Pr=exp(s-mrow) f16 (row-major), Pct=exp(s-mcol)^T f16,
// atomicAdd lrow/lcol (shuffle-pre-reduced).
__global__ __launch_bounds__(256)
void transform_kernel(const float* __restrict__ s,
                      _Float16* __restrict__ Pr, _Float16* __restrict__ Pct,
                      const unsigned* __restrict__ mrow_u,
                      const unsigned* __restrict__ mcol_u,
                      float* __restrict__ lrow, float* __restrict__ lcol, int gb0)
{
    const int b  = blockIdx.z;          // chunk-local
    const int xt = blockIdx.y;          // x tile (rows of s)
    const int yt = blockIdx.x;          // y tile (cols of s)
    const long long sb  = (long long)b * 2048 * 2048;
    const int gbL = (gb0 + b) * 2048;
    __shared__ _Float16 T[64 * 67];
    const int t   = threadIdx.x;
    const int rl  = t >> 4;             // 0..15
    const int cl  = (t & 15) * 4;       // 0..60
    const int gy0 = yt * 64 + cl;
    float mc[4];
    #pragma unroll
    for (int j = 0; j < 4; j++) mc[j] = fdec(mcol_u[gbL + gy0 + j]);
    #pragma unroll
    for (int step = 0; step < 4; step++) {
        const int xl = rl + step * 16;
        const int gx = xt * 64 + xl;
        const float mr = fdec(mrow_u[gbL + gx]);
        const floatx4 v = *(const floatx4*)&s[sb + (long long)gx * 2048 + gy0];
        float er[4];
        #pragma unroll
        for (int j = 0; j < 4; j++) er[j] = __expf(v[j] - mr);
        half4 h;
        #pragma unroll
        for (int j = 0; j < 4; j++) h[j] = f2h(er[j]);
        *(half4*)&Pr[sb + (long long)gx * 2048 + gy0] = h;
        float rs = er[0] + er[1] + er[2] + er[3];
        rs += __shfl_xor(rs, 1); rs += __shfl_xor(rs, 2);
        rs += __shfl_xor(rs, 4); rs += __shfl_xor(rs, 8);
        if ((t & 15) == 0) atomicAdd(&lrow[gbL + gx], rs);
        #pragma unroll
        for (int j = 0; j < 4; j++)
            T[(cl + j) * 67 + xl] = f2h(__expf(v[j] - mc[j]));
    }
    __syncthreads();
    #pragma unroll
    for (int it = 0; it < 2; it++) {
        const int yl = (t >> 3) + it * 32;
        const int x0 = (t & 7) * 8;
        half8 o; float cs = 0.f;
        #pragma unroll
        for (int k = 0; k < 8; k++) { _Float16 e = T[yl * 67 + x0 + k]; o[k] = e; cs += (float)e; }
        *(half8*)&Pct[sb + (long long)(yt * 64 + yl) * 2048 + xt * 64 + x0] = o;
        cs += __shfl_xor(cs, 1); cs += __shfl_xor(cs, 2); cs += __shfl_xor(cs, 4);
        if ((t & 7) == 0) atomicAdd(&lcol[gbL + yt * 64 + yl], cs);
    }
}

// ---------------------------------------------------------------------------
// 256x256 8-wave 8-phase GEMM (f16 operands, B is [N][K] row-major = B^T).
// EPI: 0 = relu -> f16 | 1 = mask -> f32 s + atomicMax stats | 3 = v/l -> f32
// ---------------------------------------------------------------------------
#define BAR   __builtin_amdgcn_s_barrier()
#define WAITL0 asm volatile("s_waitcnt lgkmcnt(0)" ::: "memory")
#define WAITV4 asm volatile("s_waitcnt vmcnt(4)" ::: "memory")
#define WAITV0 asm volatile("s_waitcnt vmcnt(0)" ::: "memory")

#define PHASE_READ_A(KHOFF, G)                                                 \
    _Pragma("unroll") for (int i = 0; i < 4; i++)                              \
        af[i] = *(const half8*)&S[ab + (KHOFF) + aBase + (G) * 2048 + i * 512];
#define PHASE_READ_B(KHOFF)                                                    \
    _Pragma("unroll") for (int j = 0; j < 4; j++)                              \
        bfr[j] = *(const half8*)&S[ab + (KHOFF) + bBase + j * 512];
#define MFMA_G(G)                                                              \
    _Pragma("unroll") for (int i = 0; i < 4; i++)                              \
        _Pragma("unroll") for (int j = 0; j < 4; j++)                          \
            acc[(G) * 4 + i][j] = __builtin_amdgcn_mfma_f32_16x16x32_f16(      \
                af[i], bfr[j], acc[(G) * 4 + i][j], 0, 0, 0);
#define STAGE_A(KOFF, BH)                                                      \
    { gl_lds16(a0 + (KOFF), &S[(BH) + eh]);                                    \
      gl_lds16(a1 + (KOFF), &S[(BH) + 4096 + eh]); }
#define STAGE_B(KOFF, BH)                                                      \
    { gl_lds16(bp0 + (KOFF), &S[32768 + (BH) + eh]);                           \
      gl_lds16(bp1 + (KOFF), &S[32768 + (BH) + 4096 + eh]); }

template<int EPI>
__global__ __launch_bounds__(512, 2)
void gemm256_kernel(const _Float16* __restrict__ Agv, const _Float16* __restrict__ Bgv,
                    void* __restrict__ Cgv,
                    unsigned* __restrict__ mrow_u, unsigned* __restrict__ mcol_u,
                    const float* __restrict__ lsum,
                    const int* __restrict__ xmask, const int* __restrict__ ymask,
                    const int* __restrict__ gflags, int gb0,
                    int K, int lda, int ldb, int ldc,
                    long long saA, long long saB, long long saC, int statL)
{
    // LDS halfword map: A: buf*16384 + kh*8192 + row*32 + hr   (64B rows)
    //                   B: 32768 + same.  (row, hr) holds global col
    //                   kh*32 + (hr ^ ((row&3)<<3)).
    __shared__ _Float16 S[65536];   // 128 KiB

    // bijective XCD-aware remap of the flat workgroup id (m204)
    const int gx = gridDim.x, gy = gridDim.y;
    const int nwg = gx * gy * (int)gridDim.z;
    int flat = ((int)blockIdx.z * gy + (int)blockIdx.y) * gx + (int)blockIdx.x;
    {
        const int q = nwg >> 3, r = nwg & 7, xc = flat & 7, o = flat >> 3;
        flat = (xc < r ? xc * (q + 1) : r * (q + 1) + (xc - r) * q) + o;
    }
    const int bx = flat % gx;
    const int by = (flat / gx) % gy;
    const int b  = flat / (gx * gy);

    const _Float16* Ag = Agv + (long long)b * saA;
    const _Float16* Bg = Bgv + (long long)b * saB;
    const int m0 = by << 8, n0 = bx << 8;

    const int t    = threadIdx.x;
    const int lane = t & 63;
    const int wave = t >> 6;        // 0..7
    const int wr   = wave >> 2;     // 0..1  (rows m0 + wr*128 .. +127)
    const int wc   = wave & 3;      // 0..3  (cols n0 + wc*64 .. +63)
    const int l16  = lane & 15;
    const int quad = lane >> 4;

    // staging precompute: thread t covers LDS bytes e0..e0+15 (it0) and
    // +8KB (it1 = rows+128); source col pre-swizzled.
    const int e0 = t << 4;
    const int eh = e0 >> 1;
    const int r0 = e0 >> 6;                                  // 0..127
    const int ch = (((e0 & 63) ^ ((r0 & 3) << 4)) >> 1);     // f16 col in K-half
    const _Float16* a0  = Ag + (long long)(m0 + r0) * lda + ch;
    const _Float16* a1  = Ag + (long long)(m0 + r0 + 128) * lda + ch;
    const _Float16* bp0 = Bg + (long long)(n0 + r0) * ldb + ch;
    const _Float16* bp1 = Bg + (long long)(n0 + r0 + 128) * ldb + ch;

    // ds-read precompute (halfword indices); row&3 == l16&3 always
    const int colh  = (quad << 3) ^ ((l16 & 3) << 3);
    const int aBase = (wr * 128 + l16) * 32 + colh;
    const int bBase = 32768 + (wc * 64 + l16) * 32 + colh;

    floatx4 acc[8][4];
    #pragma unroll
    for (int i = 0; i < 8; i++)
        #pragma unroll
        for (int j = 0; j < 4; j++)
            acc[i][j] = (floatx4){0.f, 0.f, 0.f, 0.f};

    const int NT = K >> 6;

    // prologue: tile 0 -> buf0 (A kh0, B kh0, A kh1, B kh1 = 8 loads)
    STAGE_A(0, 0); STAGE_B(0, 0); STAGE_A(32, 8192); STAGE_B(32, 8192);
    WAITV4;                 // A-kh0, B-kh0 (my oldest 4) landed
    BAR;                    // -> landed for all waves

    int buf = 0;
    for (int tt = 0; tt < NT; ++tt) {
        const bool more = (tt + 1 < NT);
        const int nk = (tt + 1) << 6;
        const int ab = buf << 14;            // halfwords
        const int nb = (buf ^ 1) << 14;
        half8 af[4], bfr[4];

        // ---- phase 0: kh0, m-group 0
        PHASE_READ_A(0, 0); PHASE_READ_B(0);
        if (more) STAGE_A(nk, nb);
        BAR; WAITL0;
        __builtin_amdgcn_s_setprio(1); MFMA_G(0); __builtin_amdgcn_s_setprio(0);
        BAR;
        // ---- phase 1: kh0, m-group 1 (bfr cached)
        PHASE_READ_A(0, 1);
        if (more) STAGE_B(nk, nb);
        BAR; WAITL0;
        __builtin_amdgcn_s_setprio(1); MFMA_G(1); __builtin_amdgcn_s_setprio(0);
        if (more) { WAITV4; } else { WAITV0; }   // this tile's kh1 halves landed
        BAR;
        // ---- phase 2: kh1, m-group 0
        PHASE_READ_A(8192, 0); PHASE_READ_B(8192);
        if (more) STAGE_A(nk + 32, nb + 8192);
        BAR; WAITL0;
        __builtin_amdgcn_s_setprio(1); MFMA_G(0); __builtin_amdgcn_s_setprio(0);
        BAR;
        // ---- phase 3: kh1, m-group 1
        PHASE_READ_A(8192, 1);
        if (more) STAGE_B(nk + 32, nb + 8192);
        BAR; WAITL0;
        __builtin_amdgcn_s_setprio(1); MFMA_G(1); __builtin_amdgcn_s_setprio(0);
        if (more) { WAITV4; }                    // next tile's kh0 halves landed
        BAR;
        buf ^= 1;
    }

    // ---- epilogue.  C/D frag: col=l16, row=quad*4+r (m89-verified)
    const int rowbase = m0 + wr * 128 + quad * 4;
    const int colbase = n0 + wc * 64 + l16;

    if (EPI == 0) {
        _Float16* C = (_Float16*)Cgv + (long long)b * saC;
        #pragma unroll
        for (int i = 0; i < 8; i++)
            #pragma unroll
            for (int j = 0; j < 4; j++)
                #pragma unroll
                for (int r = 0; r < 4; r++)
                    C[(long long)(rowbase + i * 16 + r) * ldc + colbase + j * 16] =
                        f2h(fmaxf(acc[i][j][r], 0.f));
    } else if (EPI == 3) {
        float* C = (float*)Cgv + (long long)b * saC;
        const float* ls = lsum + (long long)(gb0 + b) * statL;
        #pragma unroll
        for (int i = 0; i < 8; i++) {
            #pragma unroll
            for (int r = 0; r < 4; r++) {
                const int grow = rowbase + i * 16 + r;
                const float inv = 1.0f / ls[grow];
                #pragma unroll
                for (int j = 0; j < 4; j++)
                    C[(long long)grow * ldc + colbase + j * 16] = acc[i][j][r] * inv;
            }
        }
    } else {   // EPI == 1
        float* C = (float*)Cgv + (long long)b * saC;
        const int u8 = gflags[0];
        const unsigned char* xm8 = (const unsigned char*)xmask;
        const unsigned char* ym8 = (const unsigned char*)ymask;
        const long long sx = (long long)(gb0 + b) * statL;
        bool cmk[4];
        #pragma unroll
        for (int j = 0; j < 4; j++) {
            const int gcol = colbase + j * 16;
            cmk[j] = u8 ? (xm8 != nullptr && ym8[sx + gcol] != 0)
                        : (ymask[sx + gcol] != 0);
        }
        float colmax[4] = {-1e38f, -1e38f, -1e38f, -1e38f};
        #pragma unroll
        for (int i = 0; i < 8; i++) {
            #pragma unroll
            for (int r = 0; r < 4; r++) {
                const int grow = rowbase + i * 16 + r;
                const bool rm = u8 ? (xm8[sx + grow] != 0) : (xmask[sx + grow] != 0);
                float rowmax = -1e38f;
                #pragma unroll
                for (int j = 0; j < 4; j++) {
                    float v = acc[i][j][r];
                    v = (rm || cmk[j]) ? -1e30f : v;
                    C[(long long)grow * ldc + colbase + j * 16] = v;
                    rowmax = fmaxf(rowmax, v);
                    colmax[j] = fmaxf(colmax[j], v);
                }
                rowmax = fmaxf(rowmax, __shfl_xor(rowmax, 1));
                rowmax = fmaxf(rowmax, __shfl_xor(rowmax, 2));
                rowmax = fmaxf(rowmax, __shfl_xor(rowmax, 4));
                rowmax = fmaxf(rowmax, __shfl_xor(rowmax, 8));
                if (l16 == 0) atomicMax(&mrow_u[sx + grow], fenc(rowmax));
            }
        }
        #pragma unroll
        for (int j = 0; j < 4; j++) {
            float cm = colmax[j];
            cm = fmaxf(cm, __shfl_xor(cm, 16));
            cm = fmaxf(cm, __shfl_xor(cm, 32));
            if (quad == 0) atomicMax(&mcol_u[sx + colbase + j * 16], fenc(cm));
        }
    }
}

// ---------------------------------------------------------------------------
// fallback projection: raw (bf16|f32) inputs, 128^2 tile, relu -> f16
// ---------------------------------------------------------------------------
__global__ __launch_bounds__(256, 2)
void gemm_proj_raw(const void* __restrict__ Agv, const void* __restrict__ Bgv,
                   _Float16* __restrict__ Cg, const int* __restrict__ gflags,
                   int K, int lda, int ldb, int ldc)
{
    const int inf32 = gflags[1];
    const unsigned short* Ag16 = (const unsigned short*)Agv;
    const float*          Agf  = (const float*)Agv;
    const unsigned short* Bg16 = (const unsigned short*)Bgv;
    const float*          Bgf  = (const float*)Bgv;

    __shared__ _Float16 As[128 * 64];
    __shared__ _Float16 Bs[128 * 64];

    const int t = threadIdx.x, lane = t & 63, wave = t >> 6;
    const int wm = (wave >> 1) << 6, wn = (wave & 1) << 6;
    const int l16 = lane & 15, quad = lane >> 4;
    const int m0 = blockIdx.y * 128, n0 = blockIdx.x * 128;

    floatx4 acc[4][4];
    #pragma unroll
    for (int i = 0; i < 4; i++)
        #pragma unroll
        for (int j = 0; j < 4; j++)
            acc[i][j] = (floatx4){0.f, 0.f, 0.f, 0.f};

    for (int k0 = 0; k0 < K; k0 += 64) {
        #pragma unroll
        for (int c = t; c < 128 * 8; c += 256) {
            const int row = c >> 3, kc = (c & 7) << 3;
            half8 o;
            if (inf32) {
                const float* src = Agf + (long long)(m0 + row) * lda + k0 + kc;
                #pragma unroll
                for (int j = 0; j < 8; j++) o[j] = f2h(src[j]);
            } else {
                short8 r = *(const short8*)(Ag16 + (long long)(m0 + row) * lda + k0 + kc);
                #pragma unroll
                for (int j = 0; j < 8; j++) o[j] = f2h(b2f((unsigned short)r[j]));
            }
            *(half8*)&As[row * 64 + kc] = o;
        }
        #pragma unroll
        for (int c = t; c < 128 * 8; c += 256) {
            const int row = c >> 3, kc = (c & 7) << 3;
            half8 o;
            if (inf32) {
                const float* src = Bgf + (long long)(n0 + row) * ldb + k0 + kc;
                #pragma unroll
                for (int j = 0; j < 8; j++) o[j] = f2h(src[j]);
            } else {
                short8 r = *(const short8*)(Bg16 + (long long)(n0 + row) * ldb + k0 + kc);
                #pragma unroll
                for (int j = 0; j < 8; j++) o[j] = f2h(b2f((unsigned short)r[j]));
            }
            *(half8*)&Bs[row * 64 + kc] = o;
        }
        __syncthreads();
        #pragma unroll
        for (int kk = 0; kk < 64; kk += 32) {
            half8 af[4], bfr[4];
            #pragma unroll
            for (int i = 0; i < 4; i++)
                af[i] = *(const half8*)&As[(wm + i * 16 + l16) * 64 + kk + quad * 8];
            #pragma unroll
            for (int i = 0; i < 4; i++)
                bfr[i] = *(const half8*)&Bs[(wn + i * 16 + l16) * 64 + kk + quad * 8];
            #pragma unroll
            for (int i = 0; i < 4; i++)
                #pragma unroll
                for (int j = 0; j < 4; j++)
                    acc[i][j] = __builtin_amdgcn_mfma_f32_16x16x32_f16(af[i], bfr[j], acc[i][j], 0, 0, 0);
        }
        __syncthreads();
    }
    #pragma unroll
    for (int i = 0; i < 4; i++)
        #pragma unroll
        for (int j = 0; j < 4; j++)
            #pragma unroll
            for (int r = 0; r < 4; r++)
                Cg[(long long)(m0 + wm + i * 16 + quad * 4 + r) * ldc + n0 + wn + j * 16 + l16] =
                    f2h(fmaxf(acc[i][j][r], 0.f));
}

extern "C" void kernel_launch(void* const* d_in, const int* in_sizes, int n_in,
                              void* d_out, int out_size, void* d_ws, size_t ws_size,
                              hipStream_t stream)
{
    const int B = 16, L = 2048, D = 1024, H = 1024;
    const void* x  = d_in[0];
    const void* y  = d_in[1];
    const int* xmask = (const int*)d_in[2];
    const int* ymask = (const int*)d_in[3];
    const void* Wx = d_in[4];
    const void* Wy = d_in[5];

    // ws: px | py | xT | yT | mrow_u | lrow | mcol_u | lcol | flags |
    //     [WxH | WyH | xH | yH]  | s | Pr | Pct
    _Float16* px = (_Float16*)d_ws;
    _Float16* py = px + (size_t)B * L * H;
    _Float16* xT = py + (size_t)B * L * H;
    _Float16* yT = xT + (size_t)B * D * L;
    unsigned* mrow_u = (unsigned*)(yT + (size_t)B * D * L);
    float*    lrow   = (float*)(mrow_u + (size_t)B * L);
    unsigned* mcol_u = (unsigned*)(lrow + (size_t)B * L);
    float*    lcol   = (float*)(mcol_u + (size_t)B * L);
    int*      flags  = (int*)(lcol + (size_t)B * L);
    char*     p0     = (char*)(flags + 16);

    const long long per_batch = (long long)L * L * 4 + 2LL * L * L * 2;  // s+Pr+Pct
    const long long wlen = (long long)H * D;
    const long long xlen = (long long)B * L * D;
    const long long fixed = (long long)(p0 - (char*)d_ws);
    const long long fast_extra = 2 * wlen * 2 + 2 * xlen * 2;  // WxH,WyH,xH,yH f16

    const bool fast = ((long long)ws_size - fixed - fast_extra) >= per_batch;
    _Float16 *WxH = nullptr, *WyH = nullptr, *xH = nullptr, *yH = nullptr;
    char* dynbase = p0;
    if (fast) {
        WxH = (_Float16*)p0;
        WyH = WxH + wlen;
        xH  = WyH + wlen;
        yH  = xH + xlen;
        dynbase = (char*)(yH + xlen);
    }
    long long avail = (long long)ws_size - (long long)(dynbase - (char*)d_ws);
    int nc = (int)(avail / per_batch);
    if (nc < 1) nc = 1;
    if (nc > B) nc = B;

    float*    s   = (float*)dynbase;
    _Float16* Pr  = (_Float16*)(s + (size_t)nc * L * L);
    _Float16* Pct = Pr + (size_t)nc * L * L;

    float* yh = (float*)d_out;
    float* xh = yh + (size_t)B * L * D;

    dim3 blk(256);

    detect_kernel<<<1, 256, 0, stream>>>((const unsigned int*)xmask,
                                         (const unsigned int*)x, flags);
    init_kernel<<<dim3((B * L + 255) / 256), blk, 0, stream>>>(mrow_u, lrow, mcol_u, lcol, B * L);
    transpose_in_kernel<<<dim3(D / 64, L / 64, B), blk, 0, stream>>>(x, xT, xH, flags);
    transpose_in_kernel<<<dim3(D / 64, L / 64, B), blk, 0, stream>>>(y, yT, yH, flags);

    if (fast) {
        cvt16_kernel<<<dim3((int)(wlen / 2048)), blk, 0, stream>>>(Wx, WxH, flags, wlen);
        cvt16_kernel<<<dim3((int)(wlen / 2048)), blk, 0, stream>>>(Wy, WyH, flags, wlen);
        gemm256_kernel<0><<<dim3(H / 256, (B * L) / 256, 1), dim3(512), 0, stream>>>(
            xH, WxH, px, nullptr, nullptr, nullptr, nullptr, nullptr, flags, 0,
            D, D, D, H, 0, 0, 0, 0);
        gemm256_kernel<0><<<dim3(H / 256, (B * L) / 256, 1), dim3(512), 0, stream>>>(
            yH, WyH, py, nullptr, nullptr, nullptr, nullptr, nullptr, flags, 0,
            D, D, D, H, 0, 0, 0, 0);
    } else {
        gemm_proj_raw<<<dim3(H / 128, (B * L) / 128, 1), blk, 0, stream>>>(
            x, Wx, px, flags, D, D, D, H);
        gemm_proj_raw<<<dim3(H / 128, (B * L) / 128, 1), blk, 0, stream>>>(
            y, Wy, py, flags, D, D, D, H);
    }

    for (int b0 = 0; b0 < B; b0 += nc) {
        const int cur = (B - b0 < nc) ? (B - b0) : nc;
        // s = mask(px @ py^T) + row/col max atomics
        gemm256_kernel<1><<<dim3(L / 256, L / 256, cur), dim3(512), 0, stream>>>(
            px + (size_t)b0 * L * H, py + (size_t)b0 * L * H, s,
            mrow_u, mcol_u, nullptr, xmask, ymask, flags, b0,
            H, H, H, L, (long long)L * H, (long long)L * H, (long long)L * L, L);
        // Pr / Pct / lrow / lcol
        transform_kernel<<<dim3(L / 64, L / 64, cur), blk, 0, stream>>>(
            s, Pr, Pct, mrow_u, mcol_u, lrow, lcol, b0);
        // y_h = (Pr @ yT^T) / lrow
        gemm256_kernel<3><<<dim3(D / 256, L / 256, cur), dim3(512), 0, stream>>>(
            Pr, yT + (size_t)b0 * D * L, yh + (size_t)b0 * L * D,
            nullptr, nullptr, lrow, nullptr, nullptr, flags, b0,
            L, L, L, D, (long long)L * L, (long long)D * L, (long long)L * D, L);
        // x_h = (Pct @ xT^T) / lcol
        gemm256_kernel<3><<<dim3(D / 256, L / 256, cur), dim3(512), 0, stream>>>(
            Pct, xT + (size_t)b0 * D * L, xh + (size_t)b0 * L * D,
            nullptr, nullptr, lcol, nullptr, nullptr, flags, b0,
            L, L, L, D, (long long)L * L, (long long)D * L, (long long)L * D, L);
    }
    (void)in_sizes; (void)n_in; (void)out_size; (void)ws_size;
}

// Round 2
// 1254.039 us; speedup vs baseline: 1.5578x; 1.0297x over previous
//
#include <hip/hip_runtime.h>
#include <stdint.h>

// ---------------------------------------------------------------------------
// NonLinearCoSeqAttn: B=16, LX=LY=2048, D=H=1024
// R2 (on top of R1's 256x256 8-wave 4-phase/K-tile schedule):
//   - FIXED LDS swizzle for 64B rows: col ^= ((row>>1)&3)<<4. R1 used
//     (row&3)<<4 which collapses each quad to 4 bank-slots (x4 aliasing,
//     1.26e7 conflict cycles). New form sweeps all 8 slots x2 per quad.
//   - removed asm lgkmcnt(0) drains: compiler emits fine-grained lgkmcnt
//     between ds_read and MFMA (m97 evidence); full drain exposed LDS
//     latency serially every phase.
//   - staging gl_lds issued at phase top (before ds_reads) for longer
//     in-flight time; last K-tile peeled (no branches in hot loop,
//     vmcnt(0) only in the tail).
//   - cross-wave visibility edges: asm volatile vmcnt(N) ("memory") always
//     immediately before the guarding s_barrier. Steady state never
//     drains vmcnt to 0 (T4).
// ---------------------------------------------------------------------------

typedef short    short8  __attribute__((ext_vector_type(8)));
typedef _Float16 half8   __attribute__((ext_vector_type(8)));
typedef _Float16 half4   __attribute__((ext_vector_type(4)));
typedef float    floatx4 __attribute__((ext_vector_type(4)));

static __device__ __forceinline__ float b2f(unsigned short s) {
    union { unsigned int u; float f; } v; v.u = ((unsigned int)s) << 16; return v.f;
}
static __device__ __forceinline__ _Float16 f2h(float f) { return (_Float16)f; }
static __device__ __forceinline__ unsigned fenc(float f) {
    unsigned u = __float_as_uint(f);
    return (u & 0x80000000u) ? ~u : (u | 0x80000000u);
}
static __device__ __forceinline__ float fdec(unsigned u) {
    return __uint_as_float((u & 0x80000000u) ? (u ^ 0x80000000u) : ~u);
}
#define ENC_NEGINF 0x007FFFFFu

static __device__ __forceinline__ void gl_lds16(const _Float16* g, _Float16* l) {
    __builtin_amdgcn_global_load_lds(
        (const __attribute__((address_space(1))) void*)g,
        (__attribute__((address_space(3))) void*)l, 16, 0, 0);
}

// flags[0]: 1 => masks u8, 0 => int32.  flags[1]: 1 => inputs f32, 0 => bf16.
__global__ void detect_kernel(const unsigned int* __restrict__ xm,
                              const unsigned int* __restrict__ xv,
                              int* __restrict__ flags)
{
    __shared__ int anyBig, cnt;
    if (threadIdx.x == 0) { anyBig = 0; cnt = 0; }
    __syncthreads();
    int big = 0;
    for (int i = threadIdx.x; i < 2048; i += 256)
        if (xm[i] > 1u) big = 1;
    if (big) atomicOr(&anyBig, 1);
    int c = 0;
    for (int i = threadIdx.x; i < 4096; i += 256) {
        const unsigned lo = xv[i] & 0xFFFFu;
        const unsigned e  = (lo >> 7) & 0xFFu;
        if ((lo & 0x7FFFu) == 0u || (e >= 96u && e <= 143u)) c++;
    }
    atomicAdd(&cnt, c);
    __syncthreads();
    if (threadIdx.x == 0) { flags[0] = anyBig; flags[1] = (cnt < 3600) ? 1 : 0; }
}

__global__ void init_kernel(unsigned* __restrict__ mr, float* __restrict__ lr,
                            unsigned* __restrict__ mc, float* __restrict__ lc, int n)
{
    const int i = blockIdx.x * 256 + threadIdx.x;
    if (i < n) { mr[i] = ENC_NEGINF; mc[i] = ENC_NEGINF; lr[i] = 0.f; lc[i] = 0.f; }
}

// [B][L][D] (bf16|f32) -> [B][D][L] f16 (out); optionally also straight
// f16 copy [B][L][D] (outH) for the fast projection path.
__global__ __launch_bounds__(256)
void transpose_in_kernel(const void* __restrict__ in, _Float16* __restrict__ out,
                         _Float16* __restrict__ outH, const int* __restrict__ flags)
{
    const int b = blockIdx.z, lt = blockIdx.y, dt = blockIdx.x;
    const int inf32 = flags[1];
    __shared__ _Float16 T[64 * 67];
    const int t  = threadIdx.x;
    const int r0 = t >> 3;         // 0..31
    const int c0 = (t & 7) * 8;    // 0..56
    const unsigned short* in16 = (const unsigned short*)in + (long long)b * 2048 * 1024;
    const float*          inf  = (const float*)in + (long long)b * 2048 * 1024;
    #pragma unroll
    for (int it = 0; it < 2; it++) {
        const int ll = r0 + it * 32;
        const long long src = (long long)(lt * 64 + ll) * 1024 + dt * 64 + c0;
        _Float16 v[8];
        if (inf32) {
            const float* p = inf + src;
            #pragma unroll
            for (int k = 0; k < 8; k++) v[k] = f2h(p[k]);
        } else {
            short8 r = *(const short8*)(in16 + src);
            #pragma unroll
            for (int k = 0; k < 8; k++) v[k] = f2h(b2f((unsigned short)r[k]));
        }
        if (outH) {
            half8 o;
            #pragma unroll
            for (int k = 0; k < 8; k++) o[k] = v[k];
            *(half8*)&outH[(long long)b * 2048 * 1024 + src] = o;
        }
        #pragma unroll
        for (int k = 0; k < 8; k++) T[(c0 + k) * 67 + ll] = v[k];
    }
    __syncthreads();
    #pragma unroll
    for (int it = 0; it < 2; it++) {
        const int dl = r0 + it * 32;
        half8 o;
        #pragma unroll
        for (int k = 0; k < 8; k++) o[k] = T[dl * 67 + c0 + k];
        *(half8*)&out[(long long)b * 1024 * 2048 +
                      (long long)(dt * 64 + dl) * 2048 + lt * 64 + c0] = o;
    }
}

// (bf16|f32) -> f16, n elems (multiple of 2048)
__global__ __launch_bounds__(256)
void cvt16_kernel(const void* __restrict__ in, _Float16* __restrict__ out,
                  const int* __restrict__ flags, long long n)
{
    const long long i = (((long long)blockIdx.x * 256) + threadIdx.x) << 3;
    if (i >= n) return;
    half8 o;
    if (flags[1]) {
        const float* pf = (const float*)in + i;
        #pragma unroll
        for (int k = 0; k < 8; k++) o[k] = f2h(pf[k]);
    } else {
        short8 rr = *(const short8*)((const unsigned short*)in + i);
        #pragma unroll
        for (int k = 0; k < 8; k++) o[k] = f2h(b2f((unsigned short)rr[k]));
    }
    *(half8*)&out[i] = o;
}

// Per 64x64 s-tile: Pr=exp(s-mrow) f16 (row-major), Pct=exp(s-mcol)^T f16,
// atomicAdd lrow/lcol (shuffle-pre-reduced).
__global__ __launch_bounds__(256)
void transform_kernel(const float* __restrict__ s,
                      _Float16* __restrict__ Pr, _Float16* __restrict__ Pct,
                      const unsigned* __restrict__ mrow_u,
                      const unsigned* __restrict__ mcol_u,
                      float* __restrict__ lrow, float* __restrict__ lcol, int gb0)
{
    const int b  = blockIdx.z;          // chunk-local
    const int xt = blockIdx.y;          // x tile (rows of s)
    const int yt = blockIdx.x;          // y tile (cols of s)
    const long long sb  = (long long)b * 2048 * 2048;
    const int gbL = (gb0 + b) * 2048;
    __shared__ _Float16 T[64 * 67];
    const int t   = threadIdx.x;
    const int rl  = t >> 4;             // 0..15
    const int cl  = (t & 15) * 4;       // 0..60
    const int gy0 = yt * 64 + cl;
    float mc[4];
    #pragma unroll
    for (int j = 0; j < 4; j++) mc[j] = fdec(mcol_u[gbL + gy0 + j]);
    #pragma unroll
    for (int step = 0; step < 4; step++) {
        const int xl = rl + step * 16;
        const int gx = xt * 64 + xl;
        const float mr = fdec(mrow_u[gbL + gx]);
        const floatx4 v = *(const floatx4*)&s[sb + (long long)gx * 2048 + gy0];
        float er[4];
        #pragma unroll
        for (int j = 0; j < 4; j++) er[j] = __expf(v[j] - mr);
        half4 h;
        #pragma unroll
        for (int j = 0; j < 4; j++) h[j] = f2h(er[j]);
        *(half4*)&Pr[sb + (long long)gx * 2048 + gy0] = h;
        float rs = er[0] + er[1] + er[2] + er[3];
        rs += __shfl_xor(rs, 1); rs += __shfl_xor(rs, 2);
        rs += __shfl_xor(rs, 4); rs += __shfl_xor(rs, 8);
        if ((t & 15) == 0) atomicAdd(&lrow[gbL + gx], rs);
        #pragma unroll
        for (int j = 0; j < 4; j++)
            T[(cl + j) * 67 + xl] = f2h(__expf(v[j] - mc[j]));
    }
    __syncthreads();
    #pragma unroll
    for (int it = 0; it < 2; it++) {
        const int yl = (t >> 3) + it * 32;
        const int x0 = (t & 7) * 8;
        half8 o; float cs = 0.f;
        #pragma unroll
        for (int k = 0; k < 8; k++) { _Float16 e = T[yl * 67 + x0 + k]; o[k] = e; cs += (float)e; }
        *(half8*)&Pct[sb + (long long)(yt * 64 + yl) * 2048 + xt * 64 + x0] = o;
        cs += __shfl_xor(cs, 1); cs += __shfl_xor(cs, 2); cs += __shfl_xor(cs, 4);
        if ((t & 7) == 0) atomicAdd(&lcol[gbL + yt * 64 + yl], cs);
    }
}

// ---------------------------------------------------------------------------
// 256x256 8-wave 8-phase GEMM (f16 operands, B is [N][K] row-major = B^T).
// EPI: 0 = relu -> f16 | 1 = mask -> f32 s + atomicMax stats | 3 = v/l -> f32
// ---------------------------------------------------------------------------
#define BAR   __builtin_amdgcn_s_barrier()
#define WAITV4 asm volatile("s_waitcnt vmcnt(4)" ::: "memory")
#define WAITV0 asm volatile("s_waitcnt vmcnt(0)" ::: "memory")

#define PHASE_READ_A(KHOFF, G)                                                 \
    _Pragma("unroll") for (int i = 0; i < 4; i++)                              \
        af[i] = *(const half8*)&S[ab + (KHOFF) + aBase + (G) * 2048 + i * 512];
#define PHASE_READ_B(KHOFF)                                                    \
    _Pragma("unroll") for (int j = 0; j < 4; j++)                              \
        bfr[j] = *(const half8*)&S[ab + (KHOFF) + bBase + j * 512];
#define MFMA_G(G)                                                              \
    _Pragma("unroll") for (int i = 0; i < 4; i++)                              \
        _Pragma("unroll") for (int j = 0; j < 4; j++)                          \
            acc[(G) * 4 + i][j] = __builtin_amdgcn_mfma_f32_16x16x32_f16(      \
                af[i], bfr[j], acc[(G) * 4 + i][j], 0, 0, 0);
#define STAGE_A(KOFF, BH)                                                      \
    { gl_lds16(a0 + (KOFF), &S[(BH) + eh]);                                    \
      gl_lds16(a1 + (KOFF), &S[(BH) + 4096 + eh]); }
#define STAGE_B(KOFF, BH)                                                      \
    { gl_lds16(bp0 + (KOFF), &S[32768 + (BH) + eh]);                           \
      gl_lds16(bp1 + (KOFF), &S[32768 + (BH) + 4096 + eh]); }

template<int EPI>
__global__ __launch_bounds__(512, 2)
void gemm256_kernel(const _Float16* __restrict__ Agv, const _Float16* __restrict__ Bgv,
                    void* __restrict__ Cgv,
                    unsigned* __restrict__ mrow_u, unsigned* __restrict__ mcol_u,
                    const float* __restrict__ lsum,
                    const int* __restrict__ xmask, const int* __restrict__ ymask,
                    const int* __restrict__ gflags, int gb0,
                    int K, int lda, int ldb, int ldc,
                    long long saA, long long saB, long long saC, int statL)
{
    // LDS halfword map: A: buf*16384 + kh*8192 + row*32 + hr   (64B rows)
    //                   B: 32768 + same.  (row, hr) holds global f16 col
    //                   kh*32 + (hr ^ (((row>>1)&3)<<3)).
    // Bank slots: slot = 4*(row&1) + (quad ^ ((l16>>1)&3)) -> each quad's 16
    // lanes sweep all 8 slots exactly twice (conflict-free b128 reads).
    __shared__ _Float16 S[65536];   // 128 KiB

    // bijective XCD-aware remap of the flat workgroup id (m204)
    const int gx = gridDim.x, gy = gridDim.y;
    const int nwg = gx * gy * (int)gridDim.z;
    int flat = ((int)blockIdx.z * gy + (int)blockIdx.y) * gx + (int)blockIdx.x;
    {
        const int q = nwg >> 3, r = nwg & 7, xc = flat & 7, o = flat >> 3;
        flat = (xc < r ? xc * (q + 1) : r * (q + 1) + (xc - r) * q) + o;
    }
    const int bx = flat % gx;
    const int by = (flat / gx) % gy;
    const int b  = flat / (gx * gy);

    const _Float16* Ag = Agv + (long long)b * saA;
    const _Float16* Bg = Bgv + (long long)b * saB;
    const int m0 = by << 8, n0 = bx << 8;

    const int t    = threadIdx.x;
    const int lane = t & 63;
    const int wave = t >> 6;        // 0..7
    const int wr   = wave >> 2;     // 0..1  (rows m0 + wr*128 .. +127)
    const int wc   = wave & 3;      // 0..3  (cols n0 + wc*64 .. +63)
    const int l16  = lane & 15;
    const int quad = lane >> 4;

    // staging precompute: thread t covers LDS bytes e0..e0+15 (halves 8KB
    // apart = rows+128); source col pre-swizzled (same involution as reads).
    const int e0 = t << 4;
    const int eh = e0 >> 1;
    const int r0 = e0 >> 6;                                        // 0..127
    const int ch = (((e0 & 63) ^ (((r0 >> 1) & 3) << 4)) >> 1);    // f16 col in K-half
    const _Float16* a0  = Ag + (long long)(m0 + r0) * lda + ch;
    const _Float16* a1  = Ag + (long long)(m0 + r0 + 128) * lda + ch;
    const _Float16* bp0 = Bg + (long long)(n0 + r0) * ldb + ch;
    const _Float16* bp1 = Bg + (long long)(n0 + r0 + 128) * ldb + ch;

    // ds-read precompute (halfword indices); (row>>1)&3 == (l16>>1)&3 always
    // (row = base128/64/16 multiples + l16).
    const int colh  = (quad << 3) ^ (((l16 >> 1) & 3) << 3);
    const int aBase = (wr * 128 + l16) * 32 + colh;
    const int bBase = 32768 + (wc * 64 + l16) * 32 + colh;

    floatx4 acc[8][4];
    #pragma unroll
    for (int i = 0; i < 8; i++)
        #pragma unroll
        for (int j = 0; j < 4; j++)
            acc[i][j] = (floatx4){0.f, 0.f, 0.f, 0.f};

    const int NT = K >> 6;

    // prologue: tile 0 -> buf0 (A kh0, B kh0, A kh1, B kh1 = 8 loads)
    STAGE_A(0, 0); STAGE_B(0, 0); STAGE_A(32, 8192); STAGE_B(32, 8192);
    WAITV4;                 // kh0 (my oldest 4) landed
    BAR;                    // -> landed for all waves

    int buf = 0;
    for (int tt = 0; tt < NT - 1; ++tt) {
        const int nk = (tt + 1) << 6;
        const int ab = buf << 14;            // halfwords
        const int nb = (buf ^ 1) << 14;
        half8 af[4], bfr[4];

        // ---- phase 0: kh0, m-group 0
        STAGE_A(nk, nb);
        PHASE_READ_A(0, 0); PHASE_READ_B(0);
        BAR;
        __builtin_amdgcn_s_setprio(1); MFMA_G(0); __builtin_amdgcn_s_setprio(0);
        BAR;
        // ---- phase 1: kh0, m-group 1 (bfr cached)
        STAGE_B(nk, nb);
        PHASE_READ_A(0, 1);
        BAR;
        __builtin_amdgcn_s_setprio(1); MFMA_G(1); __builtin_amdgcn_s_setprio(0);
        WAITV4;             // this tile's kh1 halves landed (all older drained)
        BAR;
        // ---- phase 2: kh1, m-group 0
        STAGE_A(nk + 32, nb + 8192);
        PHASE_READ_A(8192, 0); PHASE_READ_B(8192);
        BAR;
        __builtin_amdgcn_s_setprio(1); MFMA_G(0); __builtin_amdgcn_s_setprio(0);
        BAR;
        // ---- phase 3: kh1, m-group 1
        STAGE_B(nk + 32, nb + 8192);
        PHASE_READ_A(8192, 1);
        BAR;
        __builtin_amdgcn_s_setprio(1); MFMA_G(1); __builtin_amdgcn_s_setprio(0);
        WAITV4;             // next tile's kh0 halves landed
        BAR;
        buf ^= 1;
    }

    // ---- final K-tile (no staging; only vmcnt(0) of the run)
    {
        const int ab = buf << 14;
        half8 af[4], bfr[4];
        PHASE_READ_A(0, 0); PHASE_READ_B(0);
        BAR;
        __builtin_amdgcn_s_setprio(1); MFMA_G(0); __builtin_amdgcn_s_setprio(0);
        BAR;
        PHASE_READ_A(0, 1);
        __builtin_amdgcn_s_setprio(1); MFMA_G(1); __builtin_amdgcn_s_setprio(0);
        WAITV0;             // kh1 of final tile landed
        BAR;
        PHASE_READ_A(8192, 0); PHASE_READ_B(8192);
        __builtin_amdgcn_s_setprio(1); MFMA_G(0); __builtin_amdgcn_s_setprio(0);
        PHASE_READ_A(8192, 1);
        __builtin_amdgcn_s_setprio(1); MFMA_G(1); __builtin_amdgcn_s_setprio(0);
    }

    // ---- epilogue.  C/D frag: col=l16, row=quad*4+r (m89-verified)
    const int rowbase = m0 + wr * 128 + quad * 4;
    const int colbase = n0 + wc * 64 + l16;

    if (EPI == 0) {
        _Float16* C = (_Float16*)Cgv + (long long)b * saC;
        #pragma unroll
        for (int i = 0; i < 8; i++)
            #pragma unroll
            for (int j = 0; j < 4; j++)
                #pragma unroll
                for (int r = 0; r < 4; r++)
                    C[(long long)(rowbase + i * 16 + r) * ldc + colbase + j * 16] =
                        f2h(fmaxf(acc[i][j][r], 0.f));
    } else if (EPI == 3) {
        float* C = (float*)Cgv + (long long)b * saC;
        const float* ls = lsum + (long long)(gb0 + b) * statL;
        #pragma unroll
        for (int i = 0; i < 8; i++) {
            #pragma unroll
            for (int r = 0; r < 4; r++) {
                const int grow = rowbase + i * 16 + r;
                const float inv = 1.0f / ls[grow];
                #pragma unroll
                for (int j = 0; j < 4; j++)
                    C[(long long)grow * ldc + colbase + j * 16] = acc[i][j][r] * inv;
            }
        }
    } else {   // EPI == 1
        float* C = (float*)Cgv + (long long)b * saC;
        const int u8 = gflags[0];
        const unsigned char* xm8 = (const unsigned char*)xmask;
        const unsigned char* ym8 = (const unsigned char*)ymask;
        const long long sx = (long long)(gb0 + b) * statL;
        bool cmk[4];
        #pragma unroll
        for (int j = 0; j < 4; j++) {
            const int gcol = colbase + j * 16;
            cmk[j] = u8 ? (ym8[sx + gcol] != 0)
                        : (ymask[sx + gcol] != 0);
        }
        float colmax[4] = {-1e38f, -1e38f, -1e38f, -1e38f};
        #pragma unroll
        for (int i = 0; i < 8; i++) {
            #pragma unroll
            for (int r = 0; r < 4; r++) {
                const int grow = rowbase + i * 16 + r;
                const bool rm = u8 ? (xm8[sx + grow] != 0) : (xmask[sx + grow] != 0);
                float rowmax = -1e38f;
                #pragma unroll
                for (int j = 0; j < 4; j++) {
                    float v = acc[i][j][r];
                    v = (rm || cmk[j]) ? -1e30f : v;
                    C[(long long)grow * ldc + colbase + j * 16] = v;
                    rowmax = fmaxf(rowmax, v);
                    colmax[j] = fmaxf(colmax[j], v);
                }
                rowmax = fmaxf(rowmax, __shfl_xor(rowmax, 1));
                rowmax = fmaxf(rowmax, __shfl_xor(rowmax, 2));
                rowmax = fmaxf(rowmax, __shfl_xor(rowmax, 4));
                rowmax = fmaxf(rowmax, __shfl_xor(rowmax, 8));
                if (l16 == 0) atomicMax(&mrow_u[sx + grow], fenc(rowmax));
            }
        }
        #pragma unroll
        for (int j = 0; j < 4; j++) {
            float cm = colmax[j];
            cm = fmaxf(cm, __shfl_xor(cm, 16));
            cm = fmaxf(cm, __shfl_xor(cm, 32));
            if (quad == 0) atomicMax(&mcol_u[sx + colbase + j * 16], fenc(cm));
        }
    }
}

// ---------------------------------------------------------------------------
// fallback projection: raw (bf16|f32) inputs, 128^2 tile, relu -> f16
// ---------------------------------------------------------------------------
__global__ __launch_bounds__(256, 2)
void gemm_proj_raw(const void* __restrict__ Agv, const void* __restrict__ Bgv,
                   _Float16* __restrict__ Cg, const int* __restrict__ gflags,
                   int K, int lda, int ldb, int ldc)
{
    const int inf32 = gflags[1];
    const unsigned short* Ag16 = (const unsigned short*)Agv;
    const float*          Agf  = (const float*)Agv;
    const unsigned short* Bg16 = (const unsigned short*)Bgv;
    const float*          Bgf  = (const float*)Bgv;

    __shared__ _Float16 As[128 * 64];
    __shared__ _Float16 Bs[128 * 64];

    const int t = threadIdx.x, lane = t & 63, wave = t >> 6;
    const int wm = (wave >> 1) << 6, wn = (wave & 1) << 6;
    const int l16 = lane & 15, quad = lane >> 4;
    const int m0 = blockIdx.y * 128, n0 = blockIdx.x * 128;

    floatx4 acc[4][4];
    #pragma unroll
    for (int i = 0; i < 4; i++)
        #pragma unroll
        for (int j = 0; j < 4; j++)
            acc[i][j] = (floatx4){0.f, 0.f, 0.f, 0.f};

    for (int k0 = 0; k0 < K; k0 += 64) {
        #pragma unroll
        for (int c = t; c < 128 * 8; c += 256) {
            const int row = c >> 3, kc = (c & 7) << 3;
            half8 o;
            if (inf32) {
                const float* src = Agf + (long long)(m0 + row) * lda + k0 + kc;
                #pragma unroll
                for (int j = 0; j < 8; j++) o[j] = f2h(src[j]);
            } else {
                short8 r = *(const short8*)(Ag16 + (long long)(m0 + row) * lda + k0 + kc);
                #pragma unroll
                for (int j = 0; j < 8; j++) o[j] = f2h(b2f((unsigned short)r[j]));
            }
            *(half8*)&As[row * 64 + kc] = o;
        }
        #pragma unroll
        for (int c = t; c < 128 * 8; c += 256) {
            const int row = c >> 3, kc = (c & 7) << 3;
            half8 o;
            if (inf32) {
                const float* src = Bgf + (long long)(n0 + row) * ldb + k0 + kc;
                #pragma unroll
                for (int j = 0; j < 8; j++) o[j] = f2h(src[j]);
            } else {
                short8 r = *(const short8*)(Bg16 + (long long)(n0 + row) * ldb + k0 + kc);
                #pragma unroll
                for (int j = 0; j < 8; j++) o[j] = f2h(b2f((unsigned short)r[j]));
            }
            *(half8*)&Bs[row * 64 + kc] = o;
        }
        __syncthreads();
        #pragma unroll
        for (int kk = 0; kk < 64; kk += 32) {
            half8 af[4], bfr[4];
            #pragma unroll
            for (int i = 0; i < 4; i++)
                af[i] = *(const half8*)&As[(wm + i * 16 + l16) * 64 + kk + quad * 8];
            #pragma unroll
            for (int i = 0; i < 4; i++)
                bfr[i] = *(const half8*)&Bs[(wn + i * 16 + l16) * 64 + kk + quad * 8];
            #pragma unroll
            for (int i = 0; i < 4; i++)
                #pragma unroll
                for (int j = 0; j < 4; j++)
                    acc[i][j] = __builtin_amdgcn_mfma_f32_16x16x32_f16(af[i], bfr[j], acc[i][j], 0, 0, 0);
        }
        __syncthreads();
    }
    #pragma unroll
    for (int i = 0; i < 4; i++)
        #pragma unroll
        for (int j = 0; j < 4; j++)
            #pragma unroll
            for (int r = 0; r < 4; r++)
                Cg[(long long)(m0 + wm + i * 16 + quad * 4 + r) * ldc + n0 + wn + j * 16 + l16] =
                    f2h(fmaxf(acc[i][j][r], 0.f));
}

extern "C" void kernel_launch(void* const* d_in, const int* in_sizes, int n_in,
                              void* d_out, int out_size, void* d_ws, size_t ws_size,
                              hipStream_t stream)
{
    const int B = 16, L = 2048, D = 1024, H = 1024;
    const void* x  = d_in[0];
    const void* y  = d_in[1];
    const int* xmask = (const int*)d_in[2];
    const int* ymask = (const int*)d_in[3];
    const void* Wx = d_in[4];
    const void* Wy = d_in[5];

    // ws: px | py | xT | yT | mrow_u | lrow | mcol_u | lcol | flags |
    //     [WxH | WyH | xH | yH]  | s | Pr | Pct
    _Float16* px = (_Float16*)d_ws;
    _Float16* py = px + (size_t)B * L * H;
    _Float16* xT = py + (size_t)B * L * H;
    _Float16* yT = xT + (size_t)B * D * L;
    unsigned* mrow_u = (unsigned*)(yT + (size_t)B * D * L);
    float*    lrow   = (float*)(mrow_u + (size_t)B * L);
    unsigned* mcol_u = (unsigned*)(lrow + (size_t)B * L);
    float*    lcol   = (float*)(mcol_u + (size_t)B * L);
    int*      flags  = (int*)(lcol + (size_t)B * L);
    char*     p0     = (char*)(flags + 16);

    const long long per_batch = (long long)L * L * 4 + 2LL * L * L * 2;  // s+Pr+Pct
    const long long wlen = (long long)H * D;
    const long long xlen = (long long)B * L * D;
    const long long fixed = (long long)(p0 - (char*)d_ws);
    const long long fast_extra = 2 * wlen * 2 + 2 * xlen * 2;  // WxH,WyH,xH,yH f16

    const bool fast = ((long long)ws_size - fixed - fast_extra) >= per_batch;
    _Float16 *WxH = nullptr, *WyH = nullptr, *xH = nullptr, *yH = nullptr;
    char* dynbase = p0;
    if (fast) {
        WxH = (_Float16*)p0;
        WyH = WxH + wlen;
        xH  = WyH + wlen;
        yH  = xH + xlen;
        dynbase = (char*)(yH + xlen);
    }
    long long avail = (long long)ws_size - (long long)(dynbase - (char*)d_ws);
    int nc = (int)(avail / per_batch);
    if (nc < 1) nc = 1;
    if (nc > B) nc = B;

    float*    s   = (float*)dynbase;
    _Float16* Pr  = (_Float16*)(s + (size_t)nc * L * L);
    _Float16* Pct = Pr + (size_t)nc * L * L;

    float* yh = (float*)d_out;
    float* xh = yh + (size_t)B * L * D;

    dim3 blk(256);

    detect_kernel<<<1, 256, 0, stream>>>((const unsigned int*)xmask,
                                         (const unsigned int*)x, flags);
    init_kernel<<<dim3((B * L + 255) / 256), blk, 0, stream>>>(mrow_u, lrow, mcol_u, lcol, B * L);
    transpose_in_kernel<<<dim3(D / 64, L / 64, B), blk, 0, stream>>>(x, xT, xH, flags);
    transpose_in_kernel<<<dim3(D / 64, L / 64, B), blk, 0, stream>>>(y, yT, yH, flags);

    if (fast) {
        cvt16_kernel<<<dim3((int)(wlen / 2048)), blk, 0, stream>>>(Wx, WxH, flags, wlen);
        cvt16_kernel<<<dim3((int)(wlen / 2048)), blk, 0, stream>>>(Wy, WyH, flags, wlen);
        gemm256_kernel<0><<<dim3(H / 256, (B * L) / 256, 1), dim3(512), 0, stream>>>(
            xH, WxH, px, nullptr, nullptr, nullptr, nullptr, nullptr, flags, 0,
            D, D, D, H, 0, 0, 0, 0);
        gemm256_kernel<0><<<dim3(H / 256, (B * L) / 256, 1), dim3(512), 0, stream>>>(
            yH, WyH, py, nullptr, nullptr, nullptr, nullptr, nullptr, flags, 0,
            D, D, D, H, 0, 0, 0, 0);
    } else {
        gemm_proj_raw<<<dim3(H / 128, (B * L) / 128, 1), blk, 0, stream>>>(
            x, Wx, px, flags, D, D, D, H);
        gemm_proj_raw<<<dim3(H / 128, (B * L) / 128, 1), blk, 0, stream>>>(
            y, Wy, py, flags, D, D, D, H);
    }

    for (int b0 = 0; b0 < B; b0 += nc) {
        const int cur = (B - b0 < nc) ? (B - b0) : nc;
        // s = mask(px @ py^T) + row/col max atomics
        gemm256_kernel<1><<<dim3(L / 256, L / 256, cur), dim3(512), 0, stream>>>(
            px + (size_t)b0 * L * H, py + (size_t)b0 * L * H, s,
            mrow_u, mcol_u, nullptr, xmask, ymask, flags, b0,
            H, H, H, L, (long long)L * H, (long long)L * H, (long long)L * L, L);
        // Pr / Pct / lrow / lcol
        transform_kernel<<<dim3(L / 64, L / 64, cur), blk, 0, stream>>>(
            s, Pr, Pct, mrow_u, mcol_u, lrow, lcol, b0);
        // y_h = (Pr @ yT^T) / lrow
        gemm256_kernel<3><<<dim3(D / 256, L / 256, cur), dim3(512), 0, stream>>>(
            Pr, yT + (size_t)b0 * D * L, yh + (size_t)b0 * L * D,
            nullptr, nullptr, lrow, nullptr, nullptr, flags, b0,
            L, L, L, D, (long long)L * L, (long long)D * L, (long long)L * D, L);
        // x_h = (Pct @ xT^T) / lcol
        gemm256_kernel<3><<<dim3(D / 256, L / 256, cur), dim3(512), 0, stream>>>(
            Pct, xT + (size_t)b0 * D * L, xh + (size_t)b0 * L * D,
            nullptr, nullptr, lcol, nullptr, nullptr, flags, b0,
            L, L, L, D, (long long)L * L, (long long)D * L, (long long)L * D, L);
    }
    (void)in_sizes; (void)n_in; (void)out_size; (void)ws_size;
}